// Round 2
// baseline (472.505 us; speedup 1.0000x reference)
//
#include <hip/hip_runtime.h>
#include <math.h>

constexpr int cB  = 16;
constexpr int cN  = 64;
constexpr int EMB = 32;
constexpr int NL  = 3;
constexpr int CDIM = 24;
constexpr int LOD = NL * CDIM;      // 72
constexpr int NB  = 10;
constexpr int H   = 150;
constexpr int CR  = 219;
constexpr int C2  = 438;
constexpr int HD  = 128;
constexpr int TBL = 8192;
constexpr float RADIUS = 2.0f;

__device__ __forceinline__ float sp5(float x) {
    // softplus(5x)/5, stable form
    return fmaxf(x, 0.0f) + 0.2f * log1pf(expf(-5.0f * fabsf(x)));
}
__device__ __forceinline__ float sp1(float x) {
    return fmaxf(x, 0.0f) + log1pf(expf(-fabsf(x)));
}

// f[bn][32] = emb_W[Z[bn]]; Pb[bn][72] = sum_i rb3[lo*32+i]*f[i]
__global__ void __launch_bounds__(128) k_prep(const int* __restrict__ Z,
                                              const float* __restrict__ emb_W,
                                              const float* __restrict__ rb3,
                                              float* __restrict__ f,
                                              float* __restrict__ Pb) {
    int bn = blockIdx.x;
    __shared__ float fl[EMB];
    int t = threadIdx.x;
    int z = Z[bn];
    if (t < EMB) { float v = emb_W[z * EMB + t]; fl[t] = v; f[bn * EMB + t] = v; }
    __syncthreads();
    if (t < LOD) {
        float s = 0.0f;
        for (int i = 0; i < EMB; ++i) s = fmaf(fl[i], rb3[t * EMB + i], s);
        Pb[bn * LOD + t] = s;
    }
}

// Wp[bn][h][lo] = sum_i rW3[h][lo*32+i] * f[bn][i]
__global__ void __launch_bounds__(256) k_Wp(const float* __restrict__ rW3,
                                            const float* __restrict__ f,
                                            float* __restrict__ Wp) {
    int h = blockIdx.x, blk = blockIdx.y;
    __shared__ float w3[2304];
    __shared__ float fb[64][EMB];
    int t = threadIdx.x;
    for (int i = t; i < 2304; i += 256) w3[i] = rW3[h * 2304 + i];
    for (int i = t; i < 64 * EMB; i += 256) fb[i >> 5][i & 31] = f[blk * 64 * EMB + i];
    __syncthreads();
    for (int o = t; o < 64 * LOD; o += 256) {
        unsigned bl = (unsigned)o / LOD, lo = (unsigned)o % LOD;
        float s = 0.0f;
        int base = lo * EMB;
        #pragma unroll
        for (int ii = 0; ii < EMB; ++ii) {
            int i = (ii + t) & 31;  // lane-staggered to avoid LDS bank conflicts
            s = fmaf(fb[bl][i], w3[base + i], s);
        }
        Wp[((size_t)(blk * 64 + bl) * H + h) * LOD + lo] = s;
    }
}

// table layer 0: basis(r_t) @ rW0 + rb0 -> sp5 -> tab[8192][150]
__global__ void __launch_bounds__(320) k_tab0(const float* __restrict__ rW0,
                                              const float* __restrict__ rb0,
                                              float* __restrict__ tab) {
    int row0 = blockIdx.x * 64;
    __shared__ float bas[64][NB];
    __shared__ float Ws[NB][160];
    __shared__ float bs[160];
    int t = threadIdx.x;
    if (t < 64) {
        float r = (float)(row0 + t) * (RADIUS / (float)(TBL - 1));
        #pragma unroll
        for (int k = 0; k < NB; ++k) {
            float d = r * 4.5f - (float)k;   // (r - k*step)/step, step = 2/9
            float v = 0.0f;
            if (fabsf(d) < 1.0f) { float cc = cosf(1.57079632679489662f * d); v = cc * cc; }
            bas[t][k] = v;
        }
    }
    for (int i = t; i < NB * 160; i += 320) {
        unsigned k = (unsigned)i / 160, j = (unsigned)i % 160;
        Ws[k][j] = (j < H) ? rW0[k * H + j] : 0.0f;
    }
    if (t < 160) bs[t] = (t < H) ? rb0[t] : 0.0f;
    __syncthreads();
    int jt = t % 10, a2 = t / 10, j0 = jt * 16;
    float acc0[16], acc1[16];
    #pragma unroll
    for (int q = 0; q < 16; ++q) { acc0[q] = 0.0f; acc1[q] = 0.0f; }
    for (int k = 0; k < NB; ++k) {
        float x0 = bas[a2][k], x1 = bas[a2 + 32][k];
        const float4* wr = reinterpret_cast<const float4*>(&Ws[k][j0]);
        #pragma unroll
        for (int q = 0; q < 4; ++q) {
            float4 w = wr[q];
            acc0[4*q+0] = fmaf(x0, w.x, acc0[4*q+0]);
            acc0[4*q+1] = fmaf(x0, w.y, acc0[4*q+1]);
            acc0[4*q+2] = fmaf(x0, w.z, acc0[4*q+2]);
            acc0[4*q+3] = fmaf(x0, w.w, acc0[4*q+3]);
            acc1[4*q+0] = fmaf(x1, w.x, acc1[4*q+0]);
            acc1[4*q+1] = fmaf(x1, w.y, acc1[4*q+1]);
            acc1[4*q+2] = fmaf(x1, w.z, acc1[4*q+2]);
            acc1[4*q+3] = fmaf(x1, w.w, acc1[4*q+3]);
        }
    }
    #pragma unroll
    for (int q = 0; q < 16; ++q) {
        int j = j0 + q;
        if (j < H) {
            tab[(size_t)(row0 + a2) * H + j]      = sp5(acc0[q] + bs[j]);
            tab[(size_t)(row0 + a2 + 32) * H + j] = sp5(acc1[q] + bs[j]);
        }
    }
}

// generic C = sp5(A[64rows x150] @ W[150x150] + bias), tile = 64 rows per block
__global__ void __launch_bounds__(320) k_lx(const float* __restrict__ A,
                                            const float* __restrict__ W,
                                            const float* __restrict__ bias,
                                            float* __restrict__ C) {
    int row0 = blockIdx.x * 64;
    __shared__ float As[64][152];
    __shared__ float Ws[32][160];
    __shared__ float bs[160];
    int t = threadIdx.x;
    for (int i = t; i < 64 * H; i += 320) {
        unsigned r = (unsigned)i / H, c = (unsigned)i % H;
        As[r][c] = A[(size_t)(row0 + r) * H + c];
    }
    if (t < 160) bs[t] = (t < H) ? bias[t] : 0.0f;
    int jt = t % 10, a2 = t / 10, j0 = jt * 16;
    float acc0[16], acc1[16];
    #pragma unroll
    for (int q = 0; q < 16; ++q) { acc0[q] = 0.0f; acc1[q] = 0.0f; }
    for (int kk = 0; kk < H; kk += 32) {
        int kend = min(32, H - kk);
        __syncthreads();
        for (int i = t; i < kend * 160; i += 320) {
            unsigned kr = (unsigned)i / 160, j = (unsigned)i % 160;
            Ws[kr][j] = (j < H) ? W[(size_t)(kk + kr) * H + j] : 0.0f;
        }
        __syncthreads();
        for (int kr = 0; kr < kend; ++kr) {
            float x0 = As[a2][kk + kr];
            float x1 = As[a2 + 32][kk + kr];
            const float4* wr = reinterpret_cast<const float4*>(&Ws[kr][j0]);
            #pragma unroll
            for (int q = 0; q < 4; ++q) {
                float4 w = wr[q];
                acc0[4*q+0] = fmaf(x0, w.x, acc0[4*q+0]);
                acc0[4*q+1] = fmaf(x0, w.y, acc0[4*q+1]);
                acc0[4*q+2] = fmaf(x0, w.z, acc0[4*q+2]);
                acc0[4*q+3] = fmaf(x0, w.w, acc0[4*q+3]);
                acc1[4*q+0] = fmaf(x1, w.x, acc1[4*q+0]);
                acc1[4*q+1] = fmaf(x1, w.y, acc1[4*q+1]);
                acc1[4*q+2] = fmaf(x1, w.z, acc1[4*q+2]);
                acc1[4*q+3] = fmaf(x1, w.w, acc1[4*q+3]);
            }
        }
    }
    #pragma unroll
    for (int q = 0; q < 16; ++q) {
        int j = j0 + q;
        if (j < H) {
            C[(size_t)(row0 + a2) * H + j]      = sp5(acc0[q] + bs[j]);
            C[(size_t)(row0 + a2 + 32) * H + j] = sp5(acc1[q] + bs[j]);
        }
    }
}

// per (b,n): mask, lerp h2(r) from table, [cnt x 150] @ Wp[b,n][150 x 72] + Pb -> P2[b][a][n][72]
__global__ void __launch_bounds__(256) k_P(const float* __restrict__ xyz,
                                           const float* __restrict__ tab,
                                           const float* __restrict__ Wp,
                                           const float* __restrict__ Pb,
                                           float* __restrict__ P2) {
    int bn = blockIdx.x;
    int b = bn >> 6, n = bn & 63;
    int t = threadIdx.x;
    __shared__ float h2s[64][152];
    __shared__ float wps[32][76];
    __shared__ float pbs[LOD];
    __shared__ float rws[64];
    __shared__ int ridx[64];
    __shared__ int alist[64];
    __shared__ int msk[64];
    __shared__ int cnt_s;

    float nx = xyz[((size_t)b * cN + n) * 3 + 0];
    float ny = xyz[((size_t)b * cN + n) * 3 + 1];
    float nz = xyz[((size_t)b * cN + n) * 3 + 2];
    if (t < 64) {
        int a = t;
        float d0 = xyz[((size_t)b * cN + a) * 3 + 0] - nx;
        float d1 = xyz[((size_t)b * cN + a) * 3 + 1] - ny;
        float d2 = xyz[((size_t)b * cN + a) * 3 + 2] - nz;
        float s = d0 * d0 + d1 * d1 + d2 * d2;
        float r = sqrtf(s + 1e-12f);
        msk[a] = (r < RADIUS) && (r > 1e-6f);
        float u = r * ((float)(TBL - 1) / RADIUS);
        int t0 = (int)u;
        if (t0 > TBL - 2) t0 = TBL - 2;
        ridx[a] = t0;
        rws[a] = u - (float)t0;
    }
    if (t < LOD) pbs[t] = Pb[bn * LOD + t];
    __syncthreads();
    if (t == 0) {
        int c = 0;
        for (int a = 0; a < 64; ++a) if (msk[a]) alist[c++] = a;
        cnt_s = c;
    }
    __syncthreads();
    int cnt = cnt_s;
    // masked rows of P2 must be exact zeros
    for (int i = t; i < 64 * LOD; i += 256) {
        int a = i / LOD;
        if (!msk[a]) P2[((size_t)(b * cN + a) * cN + n) * LOD + (i - a * LOD)] = 0.0f;
    }
    // stage interpolated h2 rows (compacted), zero-pad beyond cnt
    for (int i = t; i < 64 * H; i += 256) {
        unsigned ci = (unsigned)i / H, k = (unsigned)i % H;
        float v = 0.0f;
        if ((int)ci < cnt) {
            int a = alist[ci];
            const float* T0 = &tab[(size_t)ridx[a] * H + k];
            v = T0[0] + rws[a] * (T0[H] - T0[0]);
        }
        h2s[ci][k] = v;
    }
    int lot = t & 7, c2 = t >> 3;
    int lo0 = lot * 9;
    float acc0[9], acc1[9];
    #pragma unroll
    for (int q = 0; q < 9; ++q) { acc0[q] = 0.0f; acc1[q] = 0.0f; }
    for (int kk = 0; kk < H; kk += 32) {
        int kend = min(32, H - kk);
        __syncthreads();
        for (int i = t; i < kend * LOD; i += 256) {
            unsigned kr = (unsigned)i / LOD, lo = (unsigned)i % LOD;
            wps[kr][lo] = Wp[((size_t)bn * H + kk + kr) * LOD + lo];
        }
        __syncthreads();
        for (int kr = 0; kr < kend; ++kr) {
            float x0 = h2s[c2][kk + kr];
            float x1 = h2s[c2 + 32][kk + kr];
            #pragma unroll
            for (int q = 0; q < 9; ++q) {
                float wv = wps[kr][lo0 + q];
                acc0[q] = fmaf(x0, wv, acc0[q]);
                acc1[q] = fmaf(x1, wv, acc1[q]);
            }
        }
    }
    #pragma unroll
    for (int rr = 0; rr < 2; ++rr) {
        int c = c2 + rr * 32;
        if (c < cnt) {
            int a = alist[c];
            float* dst = &P2[((size_t)(b * cN + a) * cN + n) * LOD + lo0];
            #pragma unroll
            for (int q = 0; q < 9; ++q)
                dst[q] = (rr ? acc1[q] : acc0[q]) + pbs[lo0 + q];
        }
    }
}

// per (b,a): o[c] = sum_n P2[n][lo]*Y[n][yi], *0.125; concat body23; fused AtomResiduals
__global__ void __launch_bounds__(256) k_red(const float* __restrict__ xyz,
                                             const float* __restrict__ body23,
                                             const float* __restrict__ P2,
                                             const float* __restrict__ res_W,
                                             const float* __restrict__ res_b,
                                             float* __restrict__ feats) {
    int ba = blockIdx.x;
    int b = ba >> 6, a = ba & 63;
    int t = threadIdx.x;
    __shared__ float ym[64][12];
    __shared__ float xr[CR];
    if (t < 64) {
        int n = t;
        float ax = xyz[((size_t)b * cN + a) * 3 + 0];
        float ay = xyz[((size_t)b * cN + a) * 3 + 1];
        float az = xyz[((size_t)b * cN + a) * 3 + 2];
        float d0 = ax - xyz[((size_t)b * cN + n) * 3 + 0];
        float d1 = ay - xyz[((size_t)b * cN + n) * 3 + 1];
        float d2 = az - xyz[((size_t)b * cN + n) * 3 + 2];
        float s = d0 * d0 + d1 * d1 + d2 * d2;
        float r = sqrtf(s + 1e-12f);
        float inv = 1.0f / r;
        float x = d0 * inv, y = d1 * inv, z = d2 * inv;
        ym[n][0] = 0.28209479177387814f;
        ym[n][1] = 0.4886025119029199f * y;
        ym[n][2] = 0.4886025119029199f * z;
        ym[n][3] = 0.4886025119029199f * x;
        ym[n][4] = 1.0925484305920792f * x * y;
        ym[n][5] = 1.0925484305920792f * y * z;
        ym[n][6] = 0.31539156525252005f * (3.0f * z * z - 1.0f);
        ym[n][7] = 1.0925484305920792f * x * z;
        ym[n][8] = 0.5462742152960396f * (x * x - y * y);
    }
    __syncthreads();
    if (t < 216) {
        int lo, yi;
        if (t < 24) { lo = t; yi = 0; }
        else if (t < 96) { int q = t - 24; int o = q / 3; lo = 24 + o; yi = 1 + (q - o * 3); }
        else { int q = t - 96; int o = q / 5; lo = 48 + o; yi = 4 + (q - o * 5); }
        const float* p = &P2[(size_t)ba * cN * LOD];
        float acc = 0.0f;
        #pragma unroll 4
        for (int n = 0; n < cN; ++n)
            acc = fmaf(p[n * LOD + lo], ym[n][yi], acc);
        xr[3 + t] = acc * 0.125f;   // 1/sqrt(64)
    } else if (t < 219) {
        xr[t - 216] = body23[(size_t)ba * 3 + (t - 216)];
    }
    __syncthreads();
    if (t < CR) {
        float xv = xr[t];
        feats[(size_t)ba * C2 + t] = xv;
        float racc = res_b[t];
        for (int k = 0; k < CR; ++k)
            racc = fmaf(xr[k], res_W[k * CR + t], racc);
        feats[(size_t)ba * C2 + CR + t] = xv + sp5(racc);
    }
}

// pooled[b][ch] = sqrt(sum_a feats^2)
__global__ void __launch_bounds__(448) k_pool(const float* __restrict__ feats,
                                              float* __restrict__ pooled) {
    int b = blockIdx.x;
    int t = threadIdx.x;
    if (t < C2) {
        float s = 0.0f;
        for (int a = 0; a < cN; ++a) {
            float v = feats[(size_t)(b * cN + a) * C2 + t];
            s = fmaf(v, v, s);
        }
        pooled[b * C2 + t] = sqrtf(s);
    }
}

// collate Linear+softplus, BatchNorm(training stats)+softplus, output Linear+sigmoid
__global__ void __launch_bounds__(256) k_head(const float* __restrict__ pooled,
                                              const float* __restrict__ c_W,
                                              const float* __restrict__ c_b,
                                              const float* __restrict__ bn_g,
                                              const float* __restrict__ bn_b,
                                              const float* __restrict__ o_W,
                                              const float* __restrict__ o_b,
                                              float* __restrict__ out) {
    __shared__ float ps[cB][C2];
    __shared__ float hh[cB][HD];
    __shared__ float hh2[cB][HD];
    int t = threadIdx.x;
    for (int i = t; i < cB * C2; i += 256) ps[(unsigned)i / C2][(unsigned)i % C2] = pooled[i];
    __syncthreads();
    for (int o = t; o < cB * HD; o += 256) {
        int b = o >> 7, j = o & 127;
        float s0 = 0, s1 = 0, s2 = 0, s3 = 0;
        for (int ch = 0; ch < 436; ch += 4) {
            s0 = fmaf(ps[b][ch + 0], c_W[(ch + 0) * HD + j], s0);
            s1 = fmaf(ps[b][ch + 1], c_W[(ch + 1) * HD + j], s1);
            s2 = fmaf(ps[b][ch + 2], c_W[(ch + 2) * HD + j], s2);
            s3 = fmaf(ps[b][ch + 3], c_W[(ch + 3) * HD + j], s3);
        }
        s0 = fmaf(ps[b][436], c_W[436 * HD + j], s0);
        s1 = fmaf(ps[b][437], c_W[437 * HD + j], s1);
        hh[b][j] = sp1(((s0 + s1) + (s2 + s3)) + c_b[j]);
    }
    __syncthreads();
    if (t < HD) {
        int j = t;
        float mu = 0.0f;
        for (int bb = 0; bb < cB; ++bb) mu += hh[bb][j];
        mu *= (1.0f / cB);
        float var = 0.0f;
        for (int bb = 0; bb < cB; ++bb) { float d = hh[bb][j] - mu; var = fmaf(d, d, var); }
        var *= (1.0f / cB);
        float sc = bn_g[j] / sqrtf(var + 1e-5f);
        float bnb = bn_b[j];
        for (int bb = 0; bb < cB; ++bb)
            hh2[bb][j] = sp1((hh[bb][j] - mu) * sc + bnb);
    }
    __syncthreads();
    if (t < cB) {
        float s = o_b[0];
        for (int j = 0; j < HD; ++j) s = fmaf(hh2[t][j], o_W[j], s);
        out[t] = 1.0f / (1.0f + expf(-s));
    }
}

extern "C" void kernel_launch(void* const* d_in, const int* in_sizes, int n_in,
                              void* d_out, int out_size, void* d_ws, size_t ws_size,
                              hipStream_t stream) {
    const float* xyz    = (const float*)d_in[0];
    const int*   Z      = (const int*)d_in[1];
    const float* body23 = (const float*)d_in[2];
    const float* emb_W  = (const float*)d_in[3];
    const float* rW0    = (const float*)d_in[4];
    const float* rb0    = (const float*)d_in[5];
    const float* rW1    = (const float*)d_in[6];
    const float* rb1    = (const float*)d_in[7];
    const float* rW2    = (const float*)d_in[8];
    const float* rb2    = (const float*)d_in[9];
    const float* rW3    = (const float*)d_in[10];
    const float* rb3    = (const float*)d_in[11];
    const float* res_W  = (const float*)d_in[12];
    const float* res_b  = (const float*)d_in[13];
    const float* c_W    = (const float*)d_in[14];
    const float* c_b    = (const float*)d_in[15];
    const float* bn_g   = (const float*)d_in[16];
    const float* bn_b   = (const float*)d_in[17];
    const float* o_W    = (const float*)d_in[18];
    const float* o_b    = (const float*)d_in[19];

    float* w      = (float*)d_ws;
    float* fbuf   = w;                        // 1024*32
    float* Pbbuf  = fbuf + 32768;             // 1024*72
    float* Wp     = Pbbuf + 73728;            // 1024*150*72
    float* tabA   = Wp + 11059200;            // 8192*150
    float* tabB   = tabA + 1228800;           // 8192*150
    float* P2     = tabB + 1228800;           // 16*64*64*72
    float* feats  = P2 + 4718592;             // 1024*438
    float* pooled = feats + 448512;           // 16*438
    (void)in_sizes; (void)n_in; (void)out_size; (void)ws_size;

    k_prep<<<cB * cN, 128, 0, stream>>>(Z, emb_W, rb3, fbuf, Pbbuf);
    k_Wp<<<dim3(H, 16), 256, 0, stream>>>(rW3, fbuf, Wp);
    k_tab0<<<TBL / 64, 320, 0, stream>>>(rW0, rb0, tabA);
    k_lx<<<TBL / 64, 320, 0, stream>>>(tabA, rW1, rb1, tabB);
    k_lx<<<TBL / 64, 320, 0, stream>>>(tabB, rW2, rb2, tabA);
    k_P<<<cB * cN, 256, 0, stream>>>(xyz, tabA, Wp, Pbbuf, P2);
    k_red<<<cB * cN, 256, 0, stream>>>(xyz, body23, P2, res_W, res_b, feats);
    k_pool<<<cB, 448, 0, stream>>>(feats, pooled);
    k_head<<<1, 256, 0, stream>>>(pooled, c_W, c_b, bn_g, bn_b, o_W, o_b, (float*)d_out);
}